// Round 5
// baseline (138.174 us; speedup 1.0000x reference)
//
#include <hip/hip_runtime.h>
#include <cstdint>
#include <cstddef>

// HierarchicalDenseLayer: base = ctx @ Wcat (bf16 MFMA), A staged via
// double-buffered global_load_lds + counted vmcnt (R3 structure), with the
// weight-pack (prep) FUSED into the main grid behind a device-scope flag:
// blocks 0..159 pack wf, everyone issues first A-loads, then spins on flag.
// Residency proof (deadlock safety): LDS 34.3KB -> 4 blocks/CU; launch_bounds
// (256,4) forces VGPR<=128 -> 4 blocks/CU; grid=1024 = 4*256 all co-resident.

#define CTXD 512
#define NCOL 66          // 22 joints * 3
#define KT   16          // 512 / 32 k-steps
#define NT   5           // ceil(66/16) N-tiles (padded to 80)
#define RPB  128         // rows per block (4 waves x 32 rows)
#define LDS_STRIDE 67    // out tile stride: 66+1
#define PREP_BLOCKS 160  // 160*256 = 40960 = WF_ELEMS
#define WF_ELEMS (KT * NT * 64 * 8)

typedef __attribute__((ext_vector_type(8))) short  short8;  // 8 bf16
typedef __attribute__((ext_vector_type(4))) float  f32x4;   // MFMA accum

__device__ __forceinline__ unsigned short f2bf(float x) {
  unsigned u = __float_as_uint(x);
  return (unsigned short)((u + 0x7FFFu + ((u >> 16) & 1u)) >> 16);
}

__device__ __forceinline__ unsigned cvt2(float a, float b) {
  unsigned r;
  asm("v_cvt_pk_bf16_f32 %0, %1, %2" : "=v"(r) : "v"(a), "v"(b));
  return r;
}

__device__ __forceinline__ float tanhpi(float x) {
  // pi * tanh(x) = pi * (1 - 2/(e^{2x}+1)); safe at +/-inf
  float t = exp2f(x * 2.885390081777927f);
  return 3.1415926f - 6.2831852f * __builtin_amdgcn_rcpf(t + 1.0f);
}

__global__ __launch_bounds__(256, 4) void hdl_fused(
    const float* __restrict__ ctx,   // [B, 512]
    const float* __restrict__ W0,    // [512, 3]
    const float* __restrict__ b0,    // [3]
    const float* __restrict__ W,     // [22, 515, 3]
    const float* __restrict__ bflat, // [22*3]
    unsigned short* __restrict__ wf, // packed B frags (d_ws)
    unsigned int* __restrict__ flag, // d_ws + 81920, zeroed per launch
    float* __restrict__ out)         // [B, 66]
{
  __shared__ float smem[RPB * LDS_STRIDE];   // 34.3 KB

  const int tid  = threadIdx.x;
  const int lane = tid & 63;
  const int wave = tid >> 6;
  const int r16  = lane & 15;
  const int kg   = lane >> 4;
  const long blockRow = (long)blockIdx.x * RPB;

  // ---- fused prep: blocks 0..159 pack Wcat into MFMA B-frag order ----
  // wf[((kt*NT+nt)*64+l)*8+j] = Wcat[kt*32+(l>>4)*8+j][nt*16+(l&15)]
  if (blockIdx.x < PREP_BLOCKS) {
    int idx  = blockIdx.x * 256 + tid;       // covers WF_ELEMS exactly
    int j    = idx & 7;
    int l2   = (idx >> 3) & 63;
    int rest = idx >> 9;
    int nt   = rest % NT;
    int kt   = rest / NT;
    int k    = kt * 32 + (l2 >> 4) * 8 + j;
    int col  = nt * 16 + (l2 & 15);
    float v = 0.f;
    if (col < 3)          v = W0[k * 3 + col];
    else if (col < NCOL)  v = W[(col / 3) * 1545 + k * 3 + (col % 3)];
    wf[idx] = f2bf(v);
    __threadfence();                         // make wf stores device-visible
  }

  // wave-private staging: 2 buffers x (32 rows x 32 floats), dest linear.
  // XOR swizzle via pre-swizzled global source (rule 21); read applies same.
  float* stage = smem + wave * 2048;
  const float* srcBase =
      ctx + (blockRow + wave * 32 + (lane >> 3)) * (long)CTXD
          + (((lane & 7) ^ (lane >> 3)) << 2);

#define ISSUE_GLL(ktv, buf)                                                    \
  {                                                                            \
    _Pragma("unroll")                                                          \
    for (int j = 0; j < 4; ++j) {                                              \
      const float* s = srcBase + (size_t)(j * 8) * CTXD + (ktv) * 32;          \
      __builtin_amdgcn_global_load_lds(                                        \
          (const __attribute__((address_space(1))) void*)s,                    \
          (__attribute__((address_space(3))) void*)((buf) + j * 256),          \
          16, 0, 2 /* nt: ctx is streamed once, keep L2 for wf */);            \
    }                                                                          \
  }

  ISSUE_GLL(0, stage)                        // wf-independent: overlap spin

  // ---- flag rendezvous (raw s_barrier: no vmcnt drain of the glls) ----
  asm volatile("" ::: "memory");
  __builtin_amdgcn_s_barrier();              // prep stores complete block-wide
  if (tid == 0) {
    if (blockIdx.x < PREP_BLOCKS)
      __hip_atomic_fetch_add(flag, 1u, __ATOMIC_RELEASE,
                             __HIP_MEMORY_SCOPE_AGENT);
    while (__hip_atomic_load(flag, __ATOMIC_ACQUIRE,
                             __HIP_MEMORY_SCOPE_AGENT) < PREP_BLOCKS)
      __builtin_amdgcn_s_sleep(8);
  }
  __builtin_amdgcn_s_barrier();
  asm volatile("" ::: "memory");

  // ---- K-loop (R3): dbuf + counted vmcnt, no block barriers ----
  f32x4 acc[2][NT] = {};

#pragma unroll
  for (int kt = 0; kt < KT; ++kt) {
    const float* cur = stage + (kt & 1) * 1024;
    float* nxt = stage + ((kt + 1) & 1) * 1024;

    short8 bfr[NT];
#pragma unroll
    for (int n = 0; n < NT; ++n)
      bfr[n] = *(const short8*)(wf + (size_t)((kt * NT + n) * 64 + lane) * 8);

    if (kt < KT - 1) {
      ISSUE_GLL(kt + 1, nxt)
      // outstanding: gll(kt) x4 (oldest), bfr x5, gll(kt+1) x4 (newest)
      asm volatile("s_waitcnt vmcnt(4)" ::: "memory");
    } else {
      asm volatile("s_waitcnt vmcnt(0)" ::: "memory");
    }

#pragma unroll
    for (int m = 0; m < 2; ++m) {
      const int row = m * 16 + r16;
      const float* rbase = cur + row * 32;
      const int rx = r16 & 7;
      float4 f0 = *(const float4*)(rbase + ((((kg * 2)    ) ^ rx) << 2));
      float4 f1 = *(const float4*)(rbase + ((((kg * 2) + 1) ^ rx) << 2));
      union { short8 s; unsigned u[4]; } A;
      A.u[0] = cvt2(f0.x, f0.y);
      A.u[1] = cvt2(f0.z, f0.w);
      A.u[2] = cvt2(f1.x, f1.y);
      A.u[3] = cvt2(f1.z, f1.w);
#pragma unroll
      for (int n = 0; n < NT; ++n)
        acc[m][n] = __builtin_amdgcn_mfma_f32_16x16x32_bf16(
            A.s, bfr[n], acc[m][n], 0, 0, 0);
    }
  }

  __syncthreads();   // all waves done with staging before tile overwrite

  float bias[NT];
#pragma unroll
  for (int n = 0; n < NT; ++n) {
    int col = n * 16 + r16;
    bias[n] = (col < 3) ? b0[col] : ((col < NCOL) ? bflat[col] : 0.f);
  }

  // acc -> tile [row][col]+bias.  D layout: col=lane&15, row=(lane>>4)*4+q
#pragma unroll
  for (int m = 0; m < 2; ++m) {
#pragma unroll
    for (int n = 0; n < NT; ++n) {
      int col = n * 16 + r16;
      if (col < NCOL) {
        int rb = wave * 32 + m * 16 + kg * 4;
#pragma unroll
        for (int q = 0; q < 4; ++q)
          smem[(rb + q) * LDS_STRIDE + col] = acc[m][n][q] + bias[n];
      }
    }
  }
  __syncthreads();

  // per-row kinematic chain (1 thread per row)
  if (tid < RPB) {
    float* row = smem + tid * LDS_STRIDE;
    float J[22][3];
#pragma unroll
    for (int cc = 0; cc < 3; ++cc) J[0][cc] = tanhpi(row[cc]);

    constexpr int EP[21] = {0,2,5,8, 0,1,4,7, 0,3,6,9,12, 9,14,17,19, 9,13,16,18};
    constexpr int EC[21] = {2,5,8,11, 1,4,7,10, 3,6,9,12,15, 14,17,19,21, 13,16,18,20};
#pragma unroll
    for (int e = 0; e < 21; ++e) {
      const int p  = EP[e];
      const int ch = EC[e];
      const float* wp = W + ch * 1545 + 1536;   // W[ch][512:515][:]
#pragma unroll
      for (int cc = 0; cc < 3; ++cc) {
        float s = row[3 * ch + cc];
        s += J[p][0] * wp[cc] + J[p][1] * wp[3 + cc] + J[p][2] * wp[6 + cc];
        J[ch][cc] = tanhpi(s);
      }
    }
#pragma unroll
    for (int jj = 0; jj < 22; ++jj)
#pragma unroll
      for (int cc = 0; cc < 3; ++cc) row[3 * jj + cc] = J[jj][cc];
  }
  __syncthreads();

  // coalesced contiguous store of the block's [128 x 66] output
  const size_t outBase = (size_t)blockRow * NCOL;
  for (int i = tid; i < RPB * NCOL; i += 256) {
    int r  = i / NCOL;
    int cc = i - r * NCOL;
    out[outBase + i] = smem[r * LDS_STRIDE + cc];
  }
}

extern "C" void kernel_launch(void* const* d_in, const int* in_sizes, int n_in,
                              void* d_out, int out_size, void* d_ws, size_t ws_size,
                              hipStream_t stream) {
  const float* ctx  = (const float*)d_in[0];
  const float* W0   = (const float*)d_in[1];
  const float* b0   = (const float*)d_in[2];
  const float* W    = (const float*)d_in[3];
  const float* bfl  = (const float*)d_in[4];
  unsigned short* wf = (unsigned short*)d_ws;            // 81920 B
  unsigned int* flag = (unsigned int*)((char*)d_ws + WF_ELEMS * 2);

  // re-arm the rendezvous flag every launch (graph-capturable async memset)
  hipMemsetAsync((void*)flag, 0, sizeof(unsigned int), stream);

  int nrows = out_size / NCOL;                           // 131072
  hipLaunchKernelGGL(hdl_fused, dim3(nrows / RPB), dim3(256), 0,
                     stream, ctx, W0, b0, W, bfl, wf, flag, (float*)d_out);
}

// Round 6
// 63.087 us; speedup vs baseline: 2.1902x; 2.1902x over previous
//
#include <hip/hip_runtime.h>
#include <cstdint>
#include <cstddef>

// HierarchicalDenseLayer: base = ctx @ Wcat (bf16 MFMA), A staged via
// double-buffered global_load_lds with counted vmcnt (T3/T4) and XOR-swizzled
// layout (T2, pre-swizzled global source per rule 21); then per-row chain.
// R6 = R3 structure (best measured: 63.7us) + float4-vectorized output store.

#define CTXD 512
#define NCOL 66          // 22 joints * 3
#define KT   16          // 512 / 32 k-steps
#define NT   5           // ceil(66/16) N-tiles (padded to 80)
#define RPB  128         // rows per block (4 waves x 32 rows)
#define LDS_STRIDE 67    // out tile stride: 66+1, conflict-free column reads

typedef __attribute__((ext_vector_type(8))) short  short8;  // 8 bf16
typedef __attribute__((ext_vector_type(4))) float  f32x4;   // MFMA accum

__device__ __forceinline__ unsigned short f2bf(float x) {
  unsigned u = __float_as_uint(x);
  return (unsigned short)((u + 0x7FFFu + ((u >> 16) & 1u)) >> 16);
}

__device__ __forceinline__ unsigned cvt2(float a, float b) {
  unsigned r;
  asm("v_cvt_pk_bf16_f32 %0, %1, %2" : "=v"(r) : "v"(a), "v"(b));
  return r;
}

__device__ __forceinline__ float tanhpi(float x) {
  // pi * tanh(x) = pi * (1 - 2/(e^{2x}+1)); safe at +/-inf
  float t = exp2f(x * 2.885390081777927f);
  return 3.1415926f - 6.2831852f * __builtin_amdgcn_rcpf(t + 1.0f);
}

// ---------------------------------------------------------------------------
// Prep: pack Wcat (512 x 66 -> pad 80) into MFMA B-frag order:
// wf[((kt*NT+nt)*64+lane)*8+j] = Wcat[kt*32 + (lane>>4)*8 + j][nt*16 + (lane&15)]
// ---------------------------------------------------------------------------
__global__ void prep_wfrag(const float* __restrict__ W0,
                           const float* __restrict__ W,
                           unsigned short* __restrict__ wf) {
  int idx = blockIdx.x * blockDim.x + threadIdx.x;
  if (idx >= KT * NT * 64 * 8) return;
  int j    = idx & 7;
  int lane = (idx >> 3) & 63;
  int rest = idx >> 9;
  int nt   = rest % NT;
  int kt   = rest / NT;
  int k    = kt * 32 + (lane >> 4) * 8 + j;
  int col  = nt * 16 + (lane & 15);
  float v = 0.f;
  if (col < 3)          v = W0[k * 3 + col];
  else if (col < NCOL)  v = W[(col / 3) * (515 * 3) + k * 3 + (col % 3)];
  wf[idx] = f2bf(v);
}

// ---------------------------------------------------------------------------
// Main kernel
// ---------------------------------------------------------------------------
__global__ __launch_bounds__(256, 4) void hdl_main(
    const float* __restrict__ ctx,   // [B, 512]
    const float* __restrict__ b0,    // [3]
    const float* __restrict__ W,     // [22, 515, 3]
    const float* __restrict__ bflat, // [22*3]
    const unsigned short* __restrict__ wf,
    float* __restrict__ out)         // [B, 66]
{
  // union: [0, 8192) floats = 4 waves x 2 k-step buffers x 1024 floats;
  // whole array = 128 x 67 output tile for the epilogue.
  __shared__ float smem[RPB * LDS_STRIDE];   // 8576 floats = 34.3 KB

  const int tid  = threadIdx.x;
  const int lane = tid & 63;
  const int wave = tid >> 6;
  const int r16  = lane & 15;
  const int kg   = lane >> 4;
  const long blockRow = (long)blockIdx.x * RPB;

  f32x4 acc[2][NT] = {};

  // wave-private staging: 2 buffers x (32 rows x 32 floats), linear per gll.
  // Swizzle: LDS 16B-unit u of row r holds global unit u ^ (r&7); achieved by
  // pre-swizzling the per-lane global source (dest stays linear, rule 21).
  float* stage = smem + wave * 2048;
  // gll inst j covers rows j*8+(lane>>3); lane's 16B dest unit = lane&7
  const float* srcBase =
      ctx + (blockRow + wave * 32 + (lane >> 3)) * (long)CTXD
          + (((lane & 7) ^ (lane >> 3)) << 2);

#define ISSUE_GLL(ktv, buf)                                                    \
  {                                                                            \
    _Pragma("unroll")                                                          \
    for (int j = 0; j < 4; ++j) {                                              \
      const float* s = srcBase + (size_t)(j * 8) * CTXD + (ktv) * 32;          \
      __builtin_amdgcn_global_load_lds(                                        \
          (const __attribute__((address_space(1))) void*)s,                    \
          (__attribute__((address_space(3))) void*)((buf) + j * 256),          \
          16, 0, 0);                                                           \
    }                                                                          \
  }

  ISSUE_GLL(0, stage)                         // prologue: kt=0 in flight (4 ops)

#pragma unroll
  for (int kt = 0; kt < KT; ++kt) {
    const float* cur = stage + (kt & 1) * 1024;
    float* nxt = stage + ((kt + 1) & 1) * 1024;

    // b-frags for kt: issued BEFORE next gll batch so vmcnt(4) covers them
    short8 bfr[NT];
#pragma unroll
    for (int n = 0; n < NT; ++n)
      bfr[n] = *(const short8*)(wf + (size_t)((kt * NT + n) * 64 + lane) * 8);

    if (kt < KT - 1) {
      ISSUE_GLL(kt + 1, nxt)
      // outstanding: gll(kt) x4 (oldest), bfr(kt) x5, gll(kt+1) x4 (newest)
      asm volatile("s_waitcnt vmcnt(4)" ::: "memory");
    } else {
      asm volatile("s_waitcnt vmcnt(0)" ::: "memory");
    }

#pragma unroll
    for (int m = 0; m < 2; ++m) {
      const int row = m * 16 + r16;
      const float* rbase = cur + row * 32;
      const int rx = r16 & 7;
      float4 f0 = *(const float4*)(rbase + ((((kg * 2)     ) ^ rx) << 2));
      float4 f1 = *(const float4*)(rbase + ((((kg * 2) + 1 ) ^ rx) << 2));
      union { short8 s; unsigned u[4]; } A;
      A.u[0] = cvt2(f0.x, f0.y);
      A.u[1] = cvt2(f0.z, f0.w);
      A.u[2] = cvt2(f1.x, f1.y);
      A.u[3] = cvt2(f1.z, f1.w);
#pragma unroll
      for (int n = 0; n < NT; ++n)
        acc[m][n] = __builtin_amdgcn_mfma_f32_16x16x32_bf16(
            A.s, bfr[n], acc[m][n], 0, 0, 0);
    }
  }

  // staging region is about to be overwritten by the output tile
  __syncthreads();

  // bias loads after the counted-vmcnt section (keeps the wait counts exact)
  float bias[NT];
#pragma unroll
  for (int n = 0; n < NT; ++n) {
    int col = n * 16 + r16;
    bias[n] = (col < 3) ? b0[col] : ((col < NCOL) ? bflat[col] : 0.f);
  }

  // accum -> LDS [row][col] with +bias.  D layout: col=lane&15, row=(lane>>4)*4+reg
#pragma unroll
  for (int m = 0; m < 2; ++m) {
#pragma unroll
    for (int n = 0; n < NT; ++n) {
      int col = n * 16 + r16;
      if (col < NCOL) {
        int rb = wave * 32 + m * 16 + kg * 4;
#pragma unroll
        for (int q = 0; q < 4; ++q)
          smem[(rb + q) * LDS_STRIDE + col] = acc[m][n][q] + bias[n];
      }
    }
  }
  __syncthreads();

  // per-row kinematic chain (1 thread per row)
  if (tid < RPB) {
    float* row = smem + tid * LDS_STRIDE;
    float J[22][3];
#pragma unroll
    for (int cc = 0; cc < 3; ++cc) J[0][cc] = tanhpi(row[cc]);

    constexpr int EP[21] = {0,2,5,8, 0,1,4,7, 0,3,6,9,12, 9,14,17,19, 9,13,16,18};
    constexpr int EC[21] = {2,5,8,11, 1,4,7,10, 3,6,9,12,15, 14,17,19,21, 13,16,18,20};
#pragma unroll
    for (int e = 0; e < 21; ++e) {
      const int p  = EP[e];
      const int ch = EC[e];
      const float* wp = W + ch * 1545 + 1536;   // W[ch][512:515][:], wave-uniform
#pragma unroll
      for (int cc = 0; cc < 3; ++cc) {
        float s = row[3 * ch + cc];
        s += J[p][0] * wp[cc] + J[p][1] * wp[3 + cc] + J[p][2] * wp[6 + cc];
        J[ch][cc] = tanhpi(s);
      }
    }
#pragma unroll
    for (int jj = 0; jj < 22; ++jj)
#pragma unroll
      for (int cc = 0; cc < 3; ++cc) row[3 * jj + cc] = J[jj][cc];
  }
  __syncthreads();

  // vectorized store: 2-row units (132 floats = 33 aligned float4 each).
  // out row-pair base = outBase + p*132; p*132*4B and outBase*4B are 16B-mult.
  const size_t outBase = (size_t)blockRow * NCOL;
  for (int i = tid; i < (RPB / 2) * 33; i += 256) {
    int p = i / 33;            // row pair 0..63
    int c = i - p * 33;        // float4 chunk within pair, 0..32
    float4 v;
#pragma unroll
    for (int e = 0; e < 4; ++e) {
      int idx = c * 4 + e;             // 0..131 within the pair
      int rl  = idx >= NCOL;           // 0 or 1 (no div needed)
      int col = idx - rl * NCOL;
      ((float*)&v)[e] = smem[(p * 2 + rl) * LDS_STRIDE + col];
    }
    *(float4*)(out + outBase + (size_t)p * 132 + c * 4) = v;
  }
}

extern "C" void kernel_launch(void* const* d_in, const int* in_sizes, int n_in,
                              void* d_out, int out_size, void* d_ws, size_t ws_size,
                              hipStream_t stream) {
  const float* ctx  = (const float*)d_in[0];
  const float* W0   = (const float*)d_in[1];
  const float* b0   = (const float*)d_in[2];
  const float* W    = (const float*)d_in[3];
  const float* bfl  = (const float*)d_in[4];
  unsigned short* wf = (unsigned short*)d_ws;   // 80 KB packed weights

  int prep_elems = KT * NT * 64 * 8;            // 40960
  hipLaunchKernelGGL(prep_wfrag, dim3((prep_elems + 255) / 256), dim3(256), 0,
                     stream, W0, W, wf);

  int nrows = out_size / NCOL;                  // 131072
  hipLaunchKernelGGL(hdl_main, dim3(nrows / RPB), dim3(256), 0,
                     stream, ctx, b0, W, bfl, wf, (float*)d_out);
}